// Round 10
// baseline (139.332 us; speedup 1.0000x reference)
//
#include <hip/hip_runtime.h>
#include <math.h>

// Problem constants: B=8, L=512, H=512, NH=8, DH=64
#define Bn 8
#define Ln 512
#define Hn 512
#define NHn 8
#define DHn 64

typedef __attribute__((ext_vector_type(8))) short short8;
typedef __attribute__((ext_vector_type(4))) float f32x4;

// fp32 -> bf16 (RNE)
__device__ __forceinline__ unsigned short f2bf(float f) {
    unsigned int u = __float_as_uint(f);
    unsigned int r = (u + 0x7FFFu + ((u >> 16) & 1u)) >> 16;
    return (unsigned short)r;
}
__device__ __forceinline__ float bf2f(unsigned short s) {
    return __uint_as_float(((unsigned int)s) << 16);
}

// async global->LDS, 16 B per lane (dest = lds_base + lane*16, HW-linear)
__device__ __forceinline__ void gload16(const unsigned short* g, unsigned short* l) {
    __builtin_amdgcn_global_load_lds(
        (const __attribute__((address_space(1))) unsigned int*)g,
        (__attribute__((address_space(3))) unsigned int*)l, 16, 0, 0);
}

// ---------------------------------------------------------------------------
// Kernel 0: fp32 -> bf16 conversions (flat grid) + bias concat.
// ---------------------------------------------------------------------------
__global__ __launch_bounds__(256) void convert_kernel(
    const float* __restrict__ src, const float* __restrict__ pe,
    const float* __restrict__ Wq, const float* __restrict__ Wk,
    const float* __restrict__ Wv, const float* __restrict__ Wr,
    const float* __restrict__ bq, const float* __restrict__ bk,
    const float* __restrict__ bv,
    unsigned short* __restrict__ src_bf, unsigned short* __restrict__ pe_bf,
    unsigned short* __restrict__ Wcat_bf, unsigned short* __restrict__ Wr_bf,
    float* __restrict__ bcat)
{
    const int bid = blockIdx.x;
    const int tid = threadIdx.x;
    const float* in; unsigned short* outp; int base4;
    if (bid < 2048)      { in = src; outp = src_bf;           base4 = bid; }
    else if (bid < 2560) { in = pe;  outp = pe_bf;            base4 = bid - 2048; }
    else if (bid < 2816) { in = Wq;  outp = Wcat_bf;          base4 = bid - 2560; }
    else if (bid < 3072) { in = Wk;  outp = Wcat_bf + 262144; base4 = bid - 2816; }
    else if (bid < 3328) { in = Wv;  outp = Wcat_bf + 524288; base4 = bid - 3072; }
    else if (bid < 3584) { in = Wr;  outp = Wr_bf;            base4 = bid - 3328; }
    else {
        const int idx = (bid - 3584) * 256 + tid;   // 0..1535
        if (idx < 512)            bcat[idx] = bq[idx];
        else if (idx < 1024)      bcat[idx] = bk[idx - 512];
        else if (idx < 1536)      bcat[idx] = bv[idx - 1024];
        return;
    }
    const int i4 = (base4 * 256 + tid) * 4;
    float4 x = *(const float4*)&in[i4];
    ushort4 o;
    o.x = f2bf(x.x); o.y = f2bf(x.y); o.z = f2bf(x.z); o.w = f2bf(x.w);
    *(ushort4*)&outp[i4] = o;
}

// ---------------------------------------------------------------------------
// Kernel 1 (R17, frozen): bf16 MFMA NT-GEMM, 64x128 tile, async
// global_load_lds dbuf, XOR swizzle, counted-vmcnt protocol, dead-tile skip.
// ---------------------------------------------------------------------------
__global__ __launch_bounds__(256) void gemm_kernel(
    const unsigned short* __restrict__ src_bf,
    const unsigned short* __restrict__ Wcat_bf,
    const unsigned short* __restrict__ pe_bf,
    const unsigned short* __restrict__ Wr_bf,
    const float* __restrict__ bcat, const float* __restrict__ br,
    const int* __restrict__ seq_len,
    unsigned short* __restrict__ QKb,   // [4096][1024]
    unsigned short* __restrict__ VTg,   // [512][4096]
    unsigned short* __restrict__ Rpb)   // [1024][512]
{
    const int bid = blockIdx.x;
    int mode, m0, n0;
    const unsigned short *A, *B;
    if (bid < 512) {
        mode = 0; m0 = (bid >> 3) * 64; n0 = (bid & 7) * 128;
        if (n0 >= 512 && (m0 & 511) >= seq_len[m0 >> 9]) return;  // dead K tile
        A = src_bf + (size_t)m0 * 512;
        B = Wcat_bf + (size_t)n0 * 512;
    } else if (bid < 768) {
        const int idx = bid - 512;
        mode = 1; m0 = (idx & 7) * 64; n0 = (idx >> 3) * 128;
        if ((n0 & 511) >= seq_len[n0 >> 9]) return;               // dead V tile
        A = Wcat_bf + (size_t)(1024 + m0) * 512;
        B = src_bf + (size_t)n0 * 512;
    } else {
        const int idx = bid - 768;
        mode = 2; m0 = (idx >> 2) * 64; n0 = (idx & 3) * 128;
        A = pe_bf + (size_t)m0 * 512;
        B = Wr_bf + (size_t)n0 * 512;
    }

    // linear LDS: per buffer As 64x64 ushorts (8 KB) then Bs 128x64 (16 KB)
    __shared__ unsigned short lds[2][12288];

    const int t = threadIdx.x;
    const int wave = t >> 6, lane = t & 63;
    const int wm = (wave >> 1) * 32;
    const int wn = (wave & 1) * 64;
    const int l = lane & 15, g = lane >> 4;

    f32x4 acc[2][4] = {};

    const int lrow = lane >> 3;                 // 0..7
    const int lcol = ((lane & 7) ^ lrow) * 8;   // inverse-swizzled src col
    const unsigned short* Ag0 = A + (size_t)((wave * 2 + 0) * 8 + lrow) * 512 + lcol;
    const unsigned short* Ag1 = A + (size_t)((wave * 2 + 1) * 8 + lrow) * 512 + lcol;
    const unsigned short* Bg0 = B + (size_t)((wave * 4 + 0) * 8 + lrow) * 512 + lcol;
    const unsigned short* Bg1 = B + (size_t)((wave * 4 + 1) * 8 + lrow) * 512 + lcol;
    const unsigned short* Bg2 = B + (size_t)((wave * 4 + 2) * 8 + lrow) * 512 + lcol;
    const unsigned short* Bg3 = B + (size_t)((wave * 4 + 3) * 8 + lrow) * 512 + lcol;

    const int aB0 = (wave * 2 + 0) * 512;
    const int aB1 = (wave * 2 + 1) * 512;
    const int bB0 = 4096 + (wave * 4 + 0) * 512;
    const int bB1 = 4096 + (wave * 4 + 1) * 512;
    const int bB2 = 4096 + (wave * 4 + 2) * 512;
    const int bB3 = 4096 + (wave * 4 + 3) * 512;

    #define STAGE(buf, k0)  do {                         \
        unsigned short* Lb = &lds[buf][0];               \
        gload16(Ag0 + (k0), Lb + aB0);                   \
        gload16(Ag1 + (k0), Lb + aB1);                   \
        gload16(Bg0 + (k0), Lb + bB0);                   \
        gload16(Bg1 + (k0), Lb + bB1);                   \
        gload16(Bg2 + (k0), Lb + bB2);                   \
        gload16(Bg3 + (k0), Lb + bB3);                   \
    } while (0)

    // prologue: stage tile 0 (6 loads in flight; no drain)
    STAGE(0, 0);

    const int colA = (g ^ (lane & 7)) * 8;   // swizzled read col base

    #pragma unroll
    for (int k0 = 0; k0 < 512; k0 += 64) {
        const int cur = (k0 >> 6) & 1;
        if (k0 + 64 < 512) {
            STAGE(cur ^ 1, k0 + 64);                     // +6 in flight
            asm volatile("s_waitcnt vmcnt(6)" ::: "memory");  // cur's 6 landed
        } else {
            asm volatile("s_waitcnt vmcnt(0)" ::: "memory");  // last tile
        }
        __builtin_amdgcn_s_barrier();    // all waves' cur loads landed

        const unsigned short* Asb = &lds[cur][0];
        const unsigned short* Bsb = &lds[cur][4096];
        #pragma unroll
        for (int kk = 0; kk < 2; ++kk) {
            const int cofs = colA ^ (kk * 32);
            short8 af[2], bf[4];
            #pragma unroll
            for (int mt = 0; mt < 2; ++mt)
                af[mt] = *(const short8*)&Asb[(wm + mt * 16 + l) * 64 + cofs];
            #pragma unroll
            for (int nt = 0; nt < 4; ++nt)
                bf[nt] = *(const short8*)&Bsb[(wn + nt * 16 + l) * 64 + cofs];
            #pragma unroll
            for (int mt = 0; mt < 2; ++mt)
                #pragma unroll
                for (int nt = 0; nt < 4; ++nt)
                    acc[mt][nt] = __builtin_amdgcn_mfma_f32_16x16x32_bf16(
                        af[mt], bf[nt], acc[mt][nt], 0, 0, 0);
        }

        if (k0 + 64 < 512)
            __builtin_amdgcn_s_barrier();   // all waves done reading cur;
                                            // next iter may overwrite it
    }
    #undef STAGE

    const int crow = g * 4;
    const int ccol = l;
    if (mode == 0) {
        #pragma unroll
        for (int mt = 0; mt < 2; ++mt)
            #pragma unroll
            for (int nt = 0; nt < 4; ++nt) {
                const int n = n0 + wn + nt * 16 + ccol;
                const float bn = bcat[n];
                #pragma unroll
                for (int r = 0; r < 4; ++r) {
                    const int m = m0 + wm + mt * 16 + crow + r;
                    QKb[(size_t)m * 1024 + n] = f2bf(acc[mt][nt][r] + bn);
                }
            }
    } else if (mode == 1) {
        #pragma unroll
        for (int mt = 0; mt < 2; ++mt)
            #pragma unroll
            for (int nt = 0; nt < 4; ++nt) {
                const int n = n0 + wn + nt * 16 + ccol;      // src row (j')
                #pragma unroll
                for (int r = 0; r < 4; ++r) {
                    const int dv = m0 + wm + mt * 16 + crow + r;  // 0..511
                    VTg[(size_t)dv * 4096 + n] = f2bf(acc[mt][nt][r] + bcat[1024 + dv]);
                }
            }
    } else {
        #pragma unroll
        for (int mt = 0; mt < 2; ++mt)
            #pragma unroll
            for (int nt = 0; nt < 4; ++nt) {
                const int n = n0 + wn + nt * 16 + ccol;
                const float bn = br[n];
                #pragma unroll
                for (int r = 0; r < 4; ++r) {
                    const int m = m0 + wm + mt * 16 + crow + r;
                    Rpb[(size_t)m * 512 + n] = f2bf(acc[mt][nt][r] + bn);
                }
            }
    }
}

// ---------------------------------------------------------------------------
// Kernel 2 (R18): fixed-shift softmax attention with DOUBLE-BUFFERED staged
// tiles and ONE barrier per j-tile (was 2 + staging on the critical path).
// Per iter jt (c = jt&1): write tile jt+1 regs->buf[c^1] (overlaps compute),
// issue tile jt+2 global loads, compute on buf[c], single barrier (fences
// "all reads of c done" + "all writes of c^1 done" simultaneously).
// LDS: 2x(k,vT,rs)@64x68 + p_s@64x68 + qrTT@128x68 = 78,336 B -> 2 blk/CU.
// ---------------------------------------------------------------------------
#define PADK 68    // LDS row stride for k/v/rs/p tiles (ushorts)
#define QSTR 68    // qrTT row stride (ushorts)
__global__ __launch_bounds__(256) void attn_kernel(
    const unsigned short* __restrict__ QKb,  // [4096][1024] bf16: q|k
    const unsigned short* __restrict__ VTg,  // [512][4096] bf16 V^T
    const unsigned short* __restrict__ Rpb,  // [1024][512] bf16
    const float* __restrict__ u, const float* __restrict__ v,
    const int* __restrict__ seq_len, unsigned short* __restrict__ Ob)
{
    const int i0 = blockIdx.x * 64;
    const int h  = blockIdx.y;
    const int b  = blockIdx.z;
    const int slen = seq_len[b];
    const int njt = (slen + 63) >> 6;   // 4..8 tiles with any unmasked key

    __shared__ unsigned short k_s [2][64 * PADK];   // 2 x 8704 B
    __shared__ unsigned short vT_s[2][64 * PADK];
    __shared__ unsigned short rs_s[2][64 * PADK];
    __shared__ unsigned short p_s [64 * PADK];      // 8704 B
    __shared__ unsigned short qrTT[128 * QSTR];     // 17408 B
    // total 78,336 B -> 2 blocks/CU

    const int t = threadIdx.x;
    const int wave = t >> 6, lane = t & 63;
    const int l = lane & 15, g = lane >> 4;

    // ---- per-wave A-fragments qu=q+u, qv=q+v (registers, whole j-loop) ----
    short8 af_qu[2], af_qv[2];
    {
        const unsigned short* qrow =
            QKb + (size_t)(b * 512 + i0 + wave * 16 + l) * 1024 + h * 64;
        #pragma unroll
        for (int kk = 0; kk < 2; ++kk) {
            const int c = kk * 32 + g * 8;
            unsigned short q8[8];
            *(uint4*)q8 = *(const uint4*)(qrow + c);
            float4 u0 = *(const float4*)(u + h * 64 + c);
            float4 u1 = *(const float4*)(u + h * 64 + c + 4);
            float4 v0 = *(const float4*)(v + h * 64 + c);
            float4 v1 = *(const float4*)(v + h * 64 + c + 4);
            float uf[8] = {u0.x,u0.y,u0.z,u0.w,u1.x,u1.y,u1.z,u1.w};
            float vf[8] = {v0.x,v0.y,v0.z,v0.w,v1.x,v1.y,v1.z,v1.w};
            short8 qu, qv;
            #pragma unroll
            for (int e = 0; e < 8; ++e) {
                float qf = bf2f(q8[e]);
                qu[e] = (short)f2bf(qf + uf[e]);
                qv[e] = (short)f2bf(qf + vf[e]);
            }
            af_qu[kk] = qu; af_qv[kk] = qv;
        }
    }

    // ones-fragment (bf16 1.0) for the row-sum MFMA
    short8 ones8;
    #pragma unroll
    for (int e = 0; e < 8; ++e) ones8[e] = (short)0x3F80;

    f32x4 accO[4] = {};
    f32x4 accL = {};    // row-sums (replicated across l within a row)

    const int jr = t >> 2, c0 = (t & 3) * 16;   // staging coords

    auto btChunk = [&](int slot0, const unsigned short* rsb) {
        #pragma unroll
        for (int nt8 = 0; nt8 < 4; ++nt8) {
            f32x4 a = {};
            #pragma unroll
            for (int kk = 0; kk < 2; ++kk) {
                short8 br8 = *(const short8*)&rsb[(nt8 * 16 + l) * PADK + kk * 32 + g * 8];
                a = __builtin_amdgcn_mfma_f32_16x16x32_bf16(af_qv[kk], br8, a, 0, 0, 0);
            }
            const int sl = slot0 + nt8 * 16 + l;   // slot0 in {0,64} -> sl in [0,127]
            ushort4 w4;
            w4.x = f2bf(a[0]); w4.y = f2bf(a[1]); w4.z = f2bf(a[2]); w4.w = f2bf(a[3]);
            *(ushort4*)(qrTT + sl * QSTR + wave * 16 + g * 4) = w4;   // 4 consecutive i
        }
    };

    // ---- prologue: tile-0 k/v/rs -> buf0, chunk-A rs -> rs_s[1] ----
    {
        const unsigned short* rpA = Rpb + (size_t)(448 - i0 + jr) * 512 + h * 64 + c0;
        uint4 rA0 = *(const uint4*)(rpA);
        uint4 rA1 = *(const uint4*)(rpA + 8);
        const unsigned short* kp0 = QKb + (size_t)(b * 512 + jr) * 1024 + 512 + h * 64 + c0;
        uint4 t0 = *(const uint4*)(kp0), t1 = *(const uint4*)(kp0 + 8);
        const unsigned short* vp0 = VTg + (size_t)(h * 64 + jr) * 4096 + b * 512 + c0;
        uint4 t2 = *(const uint4*)(vp0), t3 = *(const uint4*)(vp0 + 8);
        const unsigned short* rp0 = Rpb + (size_t)(512 - i0 + jr) * 512 + h * 64 + c0;
        uint4 t4 = *(const uint4*)(rp0), t5 = *(const uint4*)(rp0 + 8);

        *(uint4*)(rs_s[1] + jr * PADK + c0)     = rA0;
        *(uint4*)(rs_s[1] + jr * PADK + c0 + 8) = rA1;
        *(uint4*)(k_s [0] + jr * PADK + c0)     = t0;
        *(uint4*)(k_s [0] + jr * PADK + c0 + 8) = t1;
        *(uint4*)(vT_s[0] + jr * PADK + c0)     = t2;
        *(uint4*)(vT_s[0] + jr * PADK + c0 + 8) = t3;
        *(uint4*)(rs_s[0] + jr * PADK + c0)     = t4;
        *(uint4*)(rs_s[0] + jr * PADK + c0 + 8) = t5;
    }

    // prefetch tile-1 into regs (njt >= 4 always; rows j0=64 in range)
    uint4 kc0, kc1, vc0, vc1, rc0, rc1;
    {
        const unsigned short* kp = QKb + (size_t)(b * 512 + 64 + jr) * 1024 + 512 + h * 64 + c0;
        kc0 = *(const uint4*)(kp); kc1 = *(const uint4*)(kp + 8);
        const unsigned short* vp = VTg + (size_t)(h * 64 + jr) * 4096 + b * 512 + 64 + c0;
        vc0 = *(const uint4*)(vp); vc1 = *(const uint4*)(vp + 8);
        const unsigned short* rp = Rpb + (size_t)(64 - i0 + 512 + jr) * 512 + h * 64 + c0;
        rc0 = *(const uint4*)(rp); rc1 = *(const uint4*)(rp + 8);
    }

    __syncthreads();                       // prologue stage visible
    btChunk((448 - i0) & 127, rs_s[1]);    // chunk-A bands
    __syncthreads();                       // rs_s[1] reads done (iter0 writes it)

    for (int jt = 0; jt < njt; ++jt) {
        const int j0 = jt * 64;
        const int c = jt & 1;

        // write tile jt+1 (in regs) into buf c^1 -- overlaps this iter's MFMAs
        if (jt + 1 < njt) {
            *(uint4*)(k_s [c ^ 1] + jr * PADK + c0)     = kc0;
            *(uint4*)(k_s [c ^ 1] + jr * PADK + c0 + 8) = kc1;
            *(uint4*)(vT_s[c ^ 1] + jr * PADK + c0)     = vc0;
            *(uint4*)(vT_s[c ^ 1] + jr * PADK + c0 + 8) = vc1;
            *(uint4*)(rs_s[c ^ 1] + jr * PADK + c0)     = rc0;
            *(uint4*)(rs_s[c ^ 1] + jr * PADK + c0 + 8) = rc1;
        }
        // issue tile jt+2 global loads (land during this iter's compute)
        if (jt + 2 < njt) {
            const unsigned short* kp =
                QKb + (size_t)(b * 512 + j0 + 128 + jr) * 1024 + 512 + h * 64 + c0;
            kc0 = *(const uint4*)(kp); kc1 = *(const uint4*)(kp + 8);
            const unsigned short* vp =
                VTg + (size_t)(h * 64 + jr) * 4096 + b * 512 + j0 + 128 + c0;
            vc0 = *(const uint4*)(vp); vc1 = *(const uint4*)(vp + 8);
            const unsigned short* rp =
                Rpb + (size_t)(j0 + 128 - i0 + 512 + jr) * 512 + h * 64 + c0;
            rc0 = *(const uint4*)(rp); rc1 = *(const uint4*)(rp + 8);
        }

        // Bt: new bands for this tile (rs buf c)
        btChunk((j0 - i0 + 512) & 127, rs_s[c]);

        // A-term: accA[nt] = qu . K^T  (k buf c)
        f32x4 accA[4];
        #pragma unroll
        for (int nt = 0; nt < 4; ++nt) {
            f32x4 a = {};
            #pragma unroll
            for (int kk = 0; kk < 2; ++kk) {
                short8 bk8 = *(const short8*)&k_s[c][(nt * 16 + l) * PADK + kk * 32 + g * 8];
                a = __builtin_amdgcn_mfma_f32_16x16x32_bf16(af_qu[kk], bk8, a, 0, 0, 0);
            }
            accA[nt] = a;
        }

        // gather rolling band + scale + mask + exp (fixed shift M=0)
        #pragma unroll
        for (int nt = 0; nt < 4; ++nt) {
            const bool masked = (j0 + nt * 16 + l) >= slen;
            #pragma unroll
            for (int r = 0; r < 4; ++r) {
                const int il = wave * 16 + g * 4 + r;
                const int slot = (j0 + nt * 16 + l - i0 - il + 512) & 127;
                const float qr = bf2f(qrTT[slot * QSTR + il]);
                const float pe_ = masked ? 0.f : __expf((accA[nt][r] + qr) * 0.125f);
                p_s[(wave * 16 + g * 4 + r) * PADK + nt * 16 + l] = f2bf(pe_);
            }
        }

        // P fragments (wave-private LDS round-trip only)
        short8 pa[2];
        #pragma unroll
        for (int kk = 0; kk < 2; ++kk)
            pa[kk] = *(const short8*)&p_s[(wave * 16 + l) * PADK + kk * 32 + g * 8];

        // row-sums via ones-MFMA
        #pragma unroll
        for (int kk = 0; kk < 2; ++kk)
            accL = __builtin_amdgcn_mfma_f32_16x16x32_bf16(pa[kk], ones8, accL, 0, 0, 0);

        // PV: accO[nt] += P . V  (vT buf c)
        #pragma unroll
        for (int nt = 0; nt < 4; ++nt) {
            #pragma unroll
            for (int kk = 0; kk < 2; ++kk) {
                short8 bv8 = *(const short8*)&vT_s[c][(nt * 16 + l) * PADK + kk * 32 + g * 8];
                accO[nt] = __builtin_amdgcn_mfma_f32_16x16x32_bf16(pa[kk], bv8, accO[nt], 0, 0, 0);
            }
        }

        // single barrier: all reads of buf c done AND writes of buf c^1 done
        if (jt + 1 < njt) __syncthreads();
    }

    // epilogue: Ob = accO / accL (bf16) -- scalar stores (R16 LDS-path regressed)
    float inv[4];
    #pragma unroll
    for (int r = 0; r < 4; ++r) inv[r] = 1.0f / accL[r];
    #pragma unroll
    for (int nt = 0; nt < 4; ++nt)
        #pragma unroll
        for (int r = 0; r < 4; ++r)
            Ob[(size_t)(b * 512 + i0 + wave * 16 + g * 4 + r) * 512 + h * 64 + nt * 16 + l]
                = f2bf(accO[nt][r] * inv[r]);
}

// ---------------------------------------------------------------------------
// Kernel 3: residual + LayerNorm + exact GELU. One wave per 512-elem row.
// ---------------------------------------------------------------------------
__global__ __launch_bounds__(256) void ln_gelu_kernel(
    const float* __restrict__ src, const unsigned short* __restrict__ Ob,
    const float* __restrict__ gamma, const float* __restrict__ beta,
    float* __restrict__ out)
{
    const int row  = blockIdx.x * 4 + (threadIdx.x >> 6);
    const int lane = threadIdx.x & 63;
    const int c0   = lane * 8;
    const float* s = &src[(size_t)row * 512 + c0];
    float4 s0 = *(const float4*)(s);
    float4 s1 = *(const float4*)(s + 4);
    unsigned short o8[8];
    *(uint4*)o8 = *(const uint4*)(Ob + (size_t)row * 512 + c0);
    float x[8];
    x[0] = s0.x + bf2f(o8[0]); x[1] = s0.y + bf2f(o8[1]);
    x[2] = s0.z + bf2f(o8[2]); x[3] = s0.w + bf2f(o8[3]);
    x[4] = s1.x + bf2f(o8[4]); x[5] = s1.y + bf2f(o8[5]);
    x[6] = s1.z + bf2f(o8[6]); x[7] = s1.w + bf2f(o8[7]);
    float sum = 0.f;
    #pragma unroll
    for (int e = 0; e < 8; ++e) sum += x[e];
    #pragma unroll
    for (int off = 32; off >= 1; off >>= 1) sum += __shfl_xor(sum, off, 64);
    const float mean = sum * (1.0f / 512.0f);
    float var = 0.f;
    #pragma unroll
    for (int e = 0; e < 8; ++e) { float d = x[e] - mean; var += d * d; }
    #pragma unroll
    for (int off = 32; off >= 1; off >>= 1) var += __shfl_xor(var, off, 64);
    var *= (1.0f / 512.0f);
    const float inv = rsqrtf(var + 1e-5f);
    float4 g0 = *(const float4*)(gamma + c0);
    float4 g1 = *(const float4*)(gamma + c0 + 4);
    float4 b0 = *(const float4*)(beta + c0);
    float4 b1 = *(const float4*)(beta + c0 + 4);
    float gm[8] = {g0.x,g0.y,g0.z,g0.w,g1.x,g1.y,g1.z,g1.w};
    float bt[8] = {b0.x,b0.y,b0.z,b0.w,b1.x,b1.y,b1.z,b1.w};
    float r8[8];
    #pragma unroll
    for (int e = 0; e < 8; ++e) {
        float ln = (x[e] - mean) * inv * gm[e] + bt[e];
        r8[e] = 0.5f * ln * (1.0f + erff(ln * 0.70710678118654752f));
    }
    float* op = &out[(size_t)row * 512 + c0];
    *(float4*)(op)     = make_float4(r8[0], r8[1], r8[2], r8[3]);
    *(float4*)(op + 4) = make_float4(r8[4], r8[5], r8[6], r8[7]);
}

// ---------------------------------------------------------------------------
extern "C" void kernel_launch(void* const* d_in, const int* in_sizes, int n_in,
                              void* d_out, int out_size, void* d_ws, size_t ws_size,
                              hipStream_t stream)
{
    const float* src     = (const float*)d_in[0];
    const int*   seq_len = (const int*)  d_in[1];
    const float* pe      = (const float*)d_in[2];
    const float* Wq      = (const float*)d_in[3];
    const float* bq      = (const float*)d_in[4];
    const float* Wk      = (const float*)d_in[5];
    const float* bk      = (const float*)d_in[6];
    const float* Wv      = (const float*)d_in[7];
    const float* bv      = (const float*)d_in[8];
    const float* Wr      = (const float*)d_in[9];
    const float* br      = (const float*)d_in[10];
    const float* u       = (const float*)d_in[11];
    const float* v       = (const float*)d_in[12];
    const float* gamma   = (const float*)d_in[13];
    const float* beta    = (const float*)d_in[14];
    float* out = (float*)d_out;

    // workspace layout (byte offsets, 16B-aligned)
    char* w = (char*)d_ws;
    unsigned short* QKb     = (unsigned short*)(w);              // 8,388,608
    unsigned short* VTg     = (unsigned short*)(w + 8388608);    // 4,194,304
    unsigned short* Rpb     = (unsigned short*)(w + 12582912);   // 1,048,576
    unsigned short* Ob      = (unsigned short*)(w + 13631488);   // 4,194,304
    unsigned short* src_bf  = (unsigned short*)(w + 17825792);   // 4,194,304
    unsigned short* pe_bf   = (unsigned short*)(w + 22020096);   // 1,048,576
    unsigned short* Wcat_bf = (unsigned short*)(w + 23068672);   // 1,572,864
    unsigned short* Wr_bf   = (unsigned short*)(w + 24641536);   //   524,288
    float*          bcat    = (float*)         (w + 25165824);   //     6,144
    // total ~25.2 MB

    convert_kernel<<<dim3(3590), 256, 0, stream>>>(
        src, pe, Wq, Wk, Wv, Wr, bq, bk, bv,
        src_bf, pe_bf, Wcat_bf, Wr_bf, bcat);

    gemm_kernel<<<dim3(832), 256, 0, stream>>>(
        src_bf, Wcat_bf, pe_bf, Wr_bf, bcat, br, seq_len, QKb, VTg, Rpb);

    attn_kernel<<<dim3(8, NHn, Bn), 256, 0, stream>>>(QKb, VTg, Rpb, u, v, seq_len, Ob);

    ln_gelu_kernel<<<dim3(Bn * Ln / 4), 256, 0, stream>>>(src, Ob, gamma, beta, out);
}

// Round 11
// 128.770 us; speedup vs baseline: 1.0820x; 1.0820x over previous
//
#include <hip/hip_runtime.h>
#include <math.h>

// Problem constants: B=8, L=512, H=512, NH=8, DH=64
#define Bn 8
#define Ln 512
#define Hn 512
#define NHn 8
#define DHn 64

typedef __attribute__((ext_vector_type(8))) short short8;
typedef __attribute__((ext_vector_type(4))) float f32x4;

// fp32 -> bf16 (RNE)
__device__ __forceinline__ unsigned short f2bf(float f) {
    unsigned int u = __float_as_uint(f);
    unsigned int r = (u + 0x7FFFu + ((u >> 16) & 1u)) >> 16;
    return (unsigned short)r;
}
__device__ __forceinline__ float bf2f(unsigned short s) {
    return __uint_as_float(((unsigned int)s) << 16);
}

// async global->LDS, 16 B per lane (dest = lds_base + lane*16, HW-linear)
__device__ __forceinline__ void gload16(const unsigned short* g, unsigned short* l) {
    __builtin_amdgcn_global_load_lds(
        (const __attribute__((address_space(1))) unsigned int*)g,
        (__attribute__((address_space(3))) unsigned int*)l, 16, 0, 0);
}

// ---------------------------------------------------------------------------
// Kernel 0: fp32 -> bf16 conversions (flat grid) + bias concat.
// ---------------------------------------------------------------------------
__global__ __launch_bounds__(256) void convert_kernel(
    const float* __restrict__ src, const float* __restrict__ pe,
    const float* __restrict__ Wq, const float* __restrict__ Wk,
    const float* __restrict__ Wv, const float* __restrict__ Wr,
    const float* __restrict__ bq, const float* __restrict__ bk,
    const float* __restrict__ bv,
    unsigned short* __restrict__ src_bf, unsigned short* __restrict__ pe_bf,
    unsigned short* __restrict__ Wcat_bf, unsigned short* __restrict__ Wr_bf,
    float* __restrict__ bcat)
{
    const int bid = blockIdx.x;
    const int tid = threadIdx.x;
    const float* in; unsigned short* outp; int base4;
    if (bid < 2048)      { in = src; outp = src_bf;           base4 = bid; }
    else if (bid < 2560) { in = pe;  outp = pe_bf;            base4 = bid - 2048; }
    else if (bid < 2816) { in = Wq;  outp = Wcat_bf;          base4 = bid - 2560; }
    else if (bid < 3072) { in = Wk;  outp = Wcat_bf + 262144; base4 = bid - 2816; }
    else if (bid < 3328) { in = Wv;  outp = Wcat_bf + 524288; base4 = bid - 3072; }
    else if (bid < 3584) { in = Wr;  outp = Wr_bf;            base4 = bid - 3328; }
    else {
        const int idx = (bid - 3584) * 256 + tid;   // 0..1535
        if (idx < 512)            bcat[idx] = bq[idx];
        else if (idx < 1024)      bcat[idx] = bk[idx - 512];
        else if (idx < 1536)      bcat[idx] = bv[idx - 1024];
        return;
    }
    const int i4 = (base4 * 256 + tid) * 4;
    float4 x = *(const float4*)&in[i4];
    ushort4 o;
    o.x = f2bf(x.x); o.y = f2bf(x.y); o.z = f2bf(x.z); o.w = f2bf(x.w);
    *(ushort4*)&outp[i4] = o;
}

// ---------------------------------------------------------------------------
// Kernel 1 (R19 = R15 + dead-tile skip): bf16 MFMA NT-GEMM, 64x128 tile,
// async global_load_lds dbuf, XOR swizzle, counted-vmcnt protocol, scalar
// epilogue. Dead-tile skip is strictly work-removing (proof in R17 notes).
// ---------------------------------------------------------------------------
__global__ __launch_bounds__(256) void gemm_kernel(
    const unsigned short* __restrict__ src_bf,
    const unsigned short* __restrict__ Wcat_bf,
    const unsigned short* __restrict__ pe_bf,
    const unsigned short* __restrict__ Wr_bf,
    const float* __restrict__ bcat, const float* __restrict__ br,
    const int* __restrict__ seq_len,
    unsigned short* __restrict__ QKb,   // [4096][1024]
    unsigned short* __restrict__ VTg,   // [512][4096]
    unsigned short* __restrict__ Rpb)   // [1024][512]
{
    const int bid = blockIdx.x;
    int mode, m0, n0;
    const unsigned short *A, *B;
    if (bid < 512) {
        mode = 0; m0 = (bid >> 3) * 64; n0 = (bid & 7) * 128;
        if (n0 >= 512 && (m0 & 511) >= seq_len[m0 >> 9]) return;  // dead K tile
        A = src_bf + (size_t)m0 * 512;
        B = Wcat_bf + (size_t)n0 * 512;
    } else if (bid < 768) {
        const int idx = bid - 512;
        mode = 1; m0 = (idx & 7) * 64; n0 = (idx >> 3) * 128;
        if ((n0 & 511) >= seq_len[n0 >> 9]) return;               // dead V tile
        A = Wcat_bf + (size_t)(1024 + m0) * 512;
        B = src_bf + (size_t)n0 * 512;
    } else {
        const int idx = bid - 768;
        mode = 2; m0 = (idx >> 2) * 64; n0 = (idx & 3) * 128;
        A = pe_bf + (size_t)m0 * 512;
        B = Wr_bf + (size_t)n0 * 512;
    }

    // linear LDS: per buffer As 64x64 ushorts (8 KB) then Bs 128x64 (16 KB)
    __shared__ unsigned short lds[2][12288];

    const int t = threadIdx.x;
    const int wave = t >> 6, lane = t & 63;
    const int wm = (wave >> 1) * 32;
    const int wn = (wave & 1) * 64;
    const int l = lane & 15, g = lane >> 4;

    f32x4 acc[2][4] = {};

    const int lrow = lane >> 3;                 // 0..7
    const int lcol = ((lane & 7) ^ lrow) * 8;   // inverse-swizzled src col
    const unsigned short* Ag0 = A + (size_t)((wave * 2 + 0) * 8 + lrow) * 512 + lcol;
    const unsigned short* Ag1 = A + (size_t)((wave * 2 + 1) * 8 + lrow) * 512 + lcol;
    const unsigned short* Bg0 = B + (size_t)((wave * 4 + 0) * 8 + lrow) * 512 + lcol;
    const unsigned short* Bg1 = B + (size_t)((wave * 4 + 1) * 8 + lrow) * 512 + lcol;
    const unsigned short* Bg2 = B + (size_t)((wave * 4 + 2) * 8 + lrow) * 512 + lcol;
    const unsigned short* Bg3 = B + (size_t)((wave * 4 + 3) * 8 + lrow) * 512 + lcol;

    const int aB0 = (wave * 2 + 0) * 512;
    const int aB1 = (wave * 2 + 1) * 512;
    const int bB0 = 4096 + (wave * 4 + 0) * 512;
    const int bB1 = 4096 + (wave * 4 + 1) * 512;
    const int bB2 = 4096 + (wave * 4 + 2) * 512;
    const int bB3 = 4096 + (wave * 4 + 3) * 512;

    #define STAGE(buf, k0)  do {                         \
        unsigned short* Lb = &lds[buf][0];               \
        gload16(Ag0 + (k0), Lb + aB0);                   \
        gload16(Ag1 + (k0), Lb + aB1);                   \
        gload16(Bg0 + (k0), Lb + bB0);                   \
        gload16(Bg1 + (k0), Lb + bB1);                   \
        gload16(Bg2 + (k0), Lb + bB2);                   \
        gload16(Bg3 + (k0), Lb + bB3);                   \
    } while (0)

    // prologue: stage tile 0 (6 loads in flight; no drain)
    STAGE(0, 0);

    const int colA = (g ^ (lane & 7)) * 8;   // swizzled read col base

    #pragma unroll
    for (int k0 = 0; k0 < 512; k0 += 64) {
        const int cur = (k0 >> 6) & 1;
        if (k0 + 64 < 512) {
            STAGE(cur ^ 1, k0 + 64);                     // +6 in flight
            asm volatile("s_waitcnt vmcnt(6)" ::: "memory");  // cur's 6 landed
        } else {
            asm volatile("s_waitcnt vmcnt(0)" ::: "memory");  // last tile
        }
        __builtin_amdgcn_s_barrier();    // all waves' cur loads landed

        const unsigned short* Asb = &lds[cur][0];
        const unsigned short* Bsb = &lds[cur][4096];
        #pragma unroll
        for (int kk = 0; kk < 2; ++kk) {
            const int cofs = colA ^ (kk * 32);
            short8 af[2], bf[4];
            #pragma unroll
            for (int mt = 0; mt < 2; ++mt)
                af[mt] = *(const short8*)&Asb[(wm + mt * 16 + l) * 64 + cofs];
            #pragma unroll
            for (int nt = 0; nt < 4; ++nt)
                bf[nt] = *(const short8*)&Bsb[(wn + nt * 16 + l) * 64 + cofs];
            #pragma unroll
            for (int mt = 0; mt < 2; ++mt)
                #pragma unroll
                for (int nt = 0; nt < 4; ++nt)
                    acc[mt][nt] = __builtin_amdgcn_mfma_f32_16x16x32_bf16(
                        af[mt], bf[nt], acc[mt][nt], 0, 0, 0);
        }

        if (k0 + 64 < 512)
            __builtin_amdgcn_s_barrier();   // all waves done reading cur;
                                            // next iter may overwrite it
    }
    #undef STAGE

    const int crow = g * 4;
    const int ccol = l;
    if (mode == 0) {
        #pragma unroll
        for (int mt = 0; mt < 2; ++mt)
            #pragma unroll
            for (int nt = 0; nt < 4; ++nt) {
                const int n = n0 + wn + nt * 16 + ccol;
                const float bn = bcat[n];
                #pragma unroll
                for (int r = 0; r < 4; ++r) {
                    const int m = m0 + wm + mt * 16 + crow + r;
                    QKb[(size_t)m * 1024 + n] = f2bf(acc[mt][nt][r] + bn);
                }
            }
    } else if (mode == 1) {
        #pragma unroll
        for (int mt = 0; mt < 2; ++mt)
            #pragma unroll
            for (int nt = 0; nt < 4; ++nt) {
                const int n = n0 + wn + nt * 16 + ccol;      // src row (j')
                #pragma unroll
                for (int r = 0; r < 4; ++r) {
                    const int dv = m0 + wm + mt * 16 + crow + r;  // 0..511
                    VTg[(size_t)dv * 4096 + n] = f2bf(acc[mt][nt][r] + bcat[1024 + dv]);
                }
            }
    } else {
        #pragma unroll
        for (int mt = 0; mt < 2; ++mt)
            #pragma unroll
            for (int nt = 0; nt < 4; ++nt) {
                const int n = n0 + wn + nt * 16 + ccol;
                const float bn = br[n];
                #pragma unroll
                for (int r = 0; r < 4; ++r) {
                    const int m = m0 + wm + mt * 16 + crow + r;
                    Rpb[(size_t)m * 512 + n] = f2bf(acc[mt][nt][r] + bn);
                }
            }
    }
}

// ---------------------------------------------------------------------------
// Kernel 2 (R19 = R12/R15 exact structure): fixed-shift softmax attention,
// PADK=72, 2-barrier staged j-loop (best measured: R15 129.07). Only change:
// exp(s*0.125) folded to exp2(s*0.125*log2e) -- one fewer VALU mul/elem.
// ---------------------------------------------------------------------------
#define PADK 72    // LDS row stride for k/v/rs/p tiles (ushorts)
__global__ __launch_bounds__(256) void attn_kernel(
    const unsigned short* __restrict__ QKb,  // [4096][1024] bf16: q|k
    const unsigned short* __restrict__ VTg,  // [512][4096] bf16 V^T
    const unsigned short* __restrict__ Rpb,  // [1024][512] bf16
    const float* __restrict__ u, const float* __restrict__ v,
    const int* __restrict__ seq_len, unsigned short* __restrict__ Ob)
{
    const int i0 = blockIdx.x * 64;
    const int h  = blockIdx.y;
    const int b  = blockIdx.z;
    const int slen = seq_len[b];
    const int njt = (slen + 63) >> 6;   // 4..8 tiles with any unmasked key

    __shared__ unsigned short k_s [64 * PADK];    // 9216 B
    __shared__ unsigned short vT_s[64 * PADK];    // 9216 B
    __shared__ unsigned short rs_s[64 * PADK];    // 9216 B
    __shared__ unsigned short p_s [64 * PADK];    // 9216 B
    __shared__ unsigned short qrTT[128 * 72];     // 18432 B  QR^T[slot][i]
    // total 55,296 B -> 2 blocks/CU

    const int t = threadIdx.x;
    const int wave = t >> 6, lane = t & 63;
    const int l = lane & 15, g = lane >> 4;

    // ---- per-wave A-fragments qu=q+u, qv=q+v (registers, whole j-loop) ----
    short8 af_qu[2], af_qv[2];
    {
        const unsigned short* qrow =
            QKb + (size_t)(b * 512 + i0 + wave * 16 + l) * 1024 + h * 64;
        #pragma unroll
        for (int kk = 0; kk < 2; ++kk) {
            const int c = kk * 32 + g * 8;
            unsigned short q8[8];
            *(uint4*)q8 = *(const uint4*)(qrow + c);
            float4 u0 = *(const float4*)(u + h * 64 + c);
            float4 u1 = *(const float4*)(u + h * 64 + c + 4);
            float4 v0 = *(const float4*)(v + h * 64 + c);
            float4 v1 = *(const float4*)(v + h * 64 + c + 4);
            float uf[8] = {u0.x,u0.y,u0.z,u0.w,u1.x,u1.y,u1.z,u1.w};
            float vf[8] = {v0.x,v0.y,v0.z,v0.w,v1.x,v1.y,v1.z,v1.w};
            short8 qu, qv;
            #pragma unroll
            for (int e = 0; e < 8; ++e) {
                float qf = bf2f(q8[e]);
                qu[e] = (short)f2bf(qf + uf[e]);
                qv[e] = (short)f2bf(qf + vf[e]);
            }
            af_qu[kk] = qu; af_qv[kk] = qv;
        }
    }

    // ones-fragment (bf16 1.0) for the row-sum MFMA
    short8 ones8;
    #pragma unroll
    for (int e = 0; e < 8; ++e) ones8[e] = (short)0x3F80;

    f32x4 accO[4] = {};
    f32x4 accL = {};    // row-sums (replicated across l within a row)

    const int jr = t >> 2, c0 = (t & 3) * 16;   // staging coords

    auto btChunk = [&](int slot0) {
        #pragma unroll
        for (int nt8 = 0; nt8 < 4; ++nt8) {
            f32x4 a = {};
            #pragma unroll
            for (int kk = 0; kk < 2; ++kk) {
                short8 br8 = *(const short8*)&rs_s[(nt8 * 16 + l) * PADK + kk * 32 + g * 8];
                a = __builtin_amdgcn_mfma_f32_16x16x32_bf16(af_qv[kk], br8, a, 0, 0, 0);
            }
            const int sl = slot0 + nt8 * 16 + l;   // slot0 in {0,64} -> sl in [0,127]
            ushort4 w4;
            w4.x = f2bf(a[0]); w4.y = f2bf(a[1]); w4.z = f2bf(a[2]); w4.w = f2bf(a[3]);
            *(ushort4*)(qrTT + sl * 72 + wave * 16 + g * 4) = w4;   // 4 consecutive i
        }
    };

    // ---- prefetch chunk-A rs + tile-0 K/V/rs into registers ----
    const unsigned short* rpA = Rpb + (size_t)(448 - i0 + jr) * 512 + h * 64 + c0;
    uint4 rA0 = *(const uint4*)(rpA);
    uint4 rA1 = *(const uint4*)(rpA + 8);
    const unsigned short* kp0 = QKb + (size_t)(b * 512 + jr) * 1024 + 512 + h * 64 + c0;
    uint4 kc0 = *(const uint4*)(kp0), kc1 = *(const uint4*)(kp0 + 8);
    const unsigned short* vp0 = VTg + (size_t)(h * 64 + jr) * 4096 + b * 512 + c0;
    uint4 vc0 = *(const uint4*)(vp0), vc1 = *(const uint4*)(vp0 + 8);
    const unsigned short* rp0 = Rpb + (size_t)(512 - i0 + jr) * 512 + h * 64 + c0;
    uint4 rc0 = *(const uint4*)(rp0), rc1 = *(const uint4*)(rp0 + 8);

    // ---- chunk A: stage + Bt for bands [448-i0, 512-i0) ----
    *(uint4*)(rs_s + jr * PADK + c0)     = rA0;
    *(uint4*)(rs_s + jr * PADK + c0 + 8) = rA1;
    __syncthreads();
    btChunk((448 - i0) & 127);

    for (int jt = 0; jt < njt; ++jt) {
        const int j0 = jt * 64;
        __syncthreads();   // all prior LDS reads done before restaging

        *(uint4*)(k_s  + jr * PADK + c0)     = kc0;
        *(uint4*)(k_s  + jr * PADK + c0 + 8) = kc1;
        *(uint4*)(vT_s + jr * PADK + c0)     = vc0;
        *(uint4*)(vT_s + jr * PADK + c0 + 8) = vc1;
        *(uint4*)(rs_s + jr * PADK + c0)     = rc0;
        *(uint4*)(rs_s + jr * PADK + c0 + 8) = rc1;
        __syncthreads();

        // prefetch next tile's globals (retire during compute below)
        if (jt + 1 < njt) {
            const unsigned short* kp =
                QKb + (size_t)(b * 512 + j0 + 64 + jr) * 1024 + 512 + h * 64 + c0;
            kc0 = *(const uint4*)(kp); kc1 = *(const uint4*)(kp + 8);
            const unsigned short* vp =
                VTg + (size_t)(h * 64 + jr) * 4096 + b * 512 + j0 + 64 + c0;
            vc0 = *(const uint4*)(vp); vc1 = *(const uint4*)(vp + 8);
            const unsigned short* rp =
                Rpb + (size_t)(j0 + 64 - i0 + 512 + jr) * 512 + h * 64 + c0;
            rc0 = *(const uint4*)(rp); rc1 = *(const uint4*)(rp + 8);
        }

        // Bt: new bands for this tile
        btChunk((j0 - i0 + 512) & 127);

        // A-term: accA[nt] = qu . K^T
        f32x4 accA[4];
        #pragma unroll
        for (int nt = 0; nt < 4; ++nt) {
            f32x4 a = {};
            #pragma unroll
            for (int kk = 0; kk < 2; ++kk) {
                short8 bk8 = *(const short8*)&k_s[(nt * 16 + l) * PADK + kk * 32 + g * 8];
                a = __builtin_amdgcn_mfma_f32_16x16x32_bf16(af_qu[kk], bk8, a, 0, 0, 0);
            }
            accA[nt] = a;
        }

        // gather rolling band + scale + mask + exp2 (fixed shift M=0;
        // 0.125*log2e folded into one constant)
        #pragma unroll
        for (int nt = 0; nt < 4; ++nt) {
            const bool masked = (j0 + nt * 16 + l) >= slen;
            #pragma unroll
            for (int r = 0; r < 4; ++r) {
                const int il = wave * 16 + g * 4 + r;
                const int slot = (j0 + nt * 16 + l - i0 - il + 512) & 127;
                const float qr = bf2f(qrTT[slot * 72 + il]);
                const float pe_ = masked ? 0.f
                    : exp2f((accA[nt][r] + qr) * 0.18033688011112042f);
                p_s[(wave * 16 + g * 4 + r) * PADK + nt * 16 + l] = f2bf(pe_);
            }
        }

        // P fragments (wave-private LDS round-trip only)
        short8 pa[2];
        #pragma unroll
        for (int kk = 0; kk < 2; ++kk)
            pa[kk] = *(const short8*)&p_s[(wave * 16 + l) * PADK + kk * 32 + g * 8];

        // row-sums via ones-MFMA
        #pragma unroll
        for (int kk = 0; kk < 2; ++kk)
            accL = __builtin_amdgcn_mfma_f32_16x16x32_bf16(pa[kk], ones8, accL, 0, 0, 0);

        // PV: accO[nt] += P . V
        #pragma unroll
        for (int nt = 0; nt < 4; ++nt) {
            #pragma unroll
            for (int kk = 0; kk < 2; ++kk) {
                short8 bv8 = *(const short8*)&vT_s[(nt * 16 + l) * PADK + kk * 32 + g * 8];
                accO[nt] = __builtin_amdgcn_mfma_f32_16x16x32_bf16(pa[kk], bv8, accO[nt], 0, 0, 0);
            }
        }
    }

    // epilogue: Ob = accO / accL (bf16)
    float inv[4];
    #pragma unroll
    for (int r = 0; r < 4; ++r) inv[r] = 1.0f / accL[r];
    #pragma unroll
    for (int nt = 0; nt < 4; ++nt)
        #pragma unroll
        for (int r = 0; r < 4; ++r)
            Ob[(size_t)(b * 512 + i0 + wave * 16 + g * 4 + r) * 512 + h * 64 + nt * 16 + l]
                = f2bf(accO[nt][r] * inv[r]);
}

// ---------------------------------------------------------------------------
// Kernel 3: residual + LayerNorm + exact GELU. One wave per 512-elem row.
// ---------------------------------------------------------------------------
__global__ __launch_bounds__(256) void ln_gelu_kernel(
    const float* __restrict__ src, const unsigned short* __restrict__ Ob,
    const float* __restrict__ gamma, const float* __restrict__ beta,
    float* __restrict__ out)
{
    const int row  = blockIdx.x * 4 + (threadIdx.x >> 6);
    const int lane = threadIdx.x & 63;
    const int c0   = lane * 8;
    const float* s = &src[(size_t)row * 512 + c0];
    float4 s0 = *(const float4*)(s);
    float4 s1 = *(const float4*)(s + 4);
    unsigned short o8[8];
    *(uint4*)o8 = *(const uint4*)(Ob + (size_t)row * 512 + c0);
    float x[8];
    x[0] = s0.x + bf2f(o8[0]); x[1] = s0.y + bf2f(o8[1]);
    x[2] = s0.z + bf2f(o8[2]); x[3] = s0.w + bf2f(o8[3]);
    x[4] = s1.x + bf2f(o8[4]); x[5] = s1.y + bf2f(o8[5]);
    x[6] = s1.z + bf2f(o8[6]); x[7] = s1.w + bf2f(o8[7]);
    float sum = 0.f;
    #pragma unroll
    for (int e = 0; e < 8; ++e) sum += x[e];
    #pragma unroll
    for (int off = 32; off >= 1; off >>= 1) sum += __shfl_xor(sum, off, 64);
    const float mean = sum * (1.0f / 512.0f);
    float var = 0.f;
    #pragma unroll
    for (int e = 0; e < 8; ++e) { float d = x[e] - mean; var += d * d; }
    #pragma unroll
    for (int off = 32; off >= 1; off >>= 1) var += __shfl_xor(var, off, 64);
    var *= (1.0f / 512.0f);
    const float inv = rsqrtf(var + 1e-5f);
    float4 g0 = *(const float4*)(gamma + c0);
    float4 g1 = *(const float4*)(gamma + c0 + 4);
    float4 b0 = *(const float4*)(beta + c0);
    float4 b1 = *(const float4*)(beta + c0 + 4);
    float gm[8] = {g0.x,g0.y,g0.z,g0.w,g1.x,g1.y,g1.z,g1.w};
    float bt[8] = {b0.x,b0.y,b0.z,b0.w,b1.x,b1.y,b1.z,b1.w};
    float r8[8];
    #pragma unroll
    for (int e = 0; e < 8; ++e) {
        float ln = (x[e] - mean) * inv * gm[e] + bt[e];
        r8[e] = 0.5f * ln * (1.0f + erff(ln * 0.70710678118654752f));
    }
    float* op = &out[(size_t)row * 512 + c0];
    *(float4*)(op)     = make_float4(r8[0], r8[1], r8[2], r8[3]);
    *(float4*)(op + 4) = make_float4(r8[4], r8[5], r8[6], r8[7]);
}

// ---------------------------------------------------------------------------
extern "C" void kernel_launch(void* const* d_in, const int* in_sizes, int n_in,
                              void* d_out, int out_size, void* d_ws, size_t ws_size,
                              hipStream_t stream)
{
    const float* src     = (const float*)d_in[0];
    const int*   seq_len = (const int*)  d_in[1];
    const float* pe      = (const float*)d_in[2];
    const float* Wq      = (const float*)d_in[3];
    const float* bq      = (const float*)d_in[4];
    const float* Wk      = (const float*)d_in[5];
    const float* bk      = (const float*)d_in[6];
    const float* Wv      = (const float*)d_in[7];
    const float* bv      = (const float*)d_in[8];
    const float* Wr      = (const float*)d_in[9];
    const float* br      = (const float*)d_in[10];
    const float* u       = (const float*)d_in[11];
    const float* v       = (const float*)d_in[12];
    const float* gamma   = (const float*)d_in[13];
    const float* beta    = (const float*)d_in[14];
    float* out = (float*)d_out;

    // workspace layout (byte offsets, 16B-aligned)
    char* w = (char*)d_ws;
    unsigned short* QKb     = (unsigned short*)(w);              // 8,388,608
    unsigned short* VTg     = (unsigned short*)(w + 8388608);    // 4,194,304
    unsigned short* Rpb     = (unsigned short*)(w + 12582912);   // 1,048,576
    unsigned short* Ob      = (unsigned short*)(w + 13631488);   // 4,194,304
    unsigned short* src_bf  = (unsigned short*)(w + 17825792);   // 4,194,304
    unsigned short* pe_bf   = (unsigned short*)(w + 22020096);   // 1,048,576
    unsigned short* Wcat_bf = (unsigned short*)(w + 23068672);   // 1,572,864
    unsigned short* Wr_bf   = (unsigned short*)(w + 24641536);   //   524,288
    float*          bcat    = (float*)         (w + 25165824);   //     6,144
    // total ~25.2 MB

    convert_kernel<<<dim3(3590), 256, 0, stream>>>(
        src, pe, Wq, Wk, Wv, Wr, bq, bk, bv,
        src_bf, pe_bf, Wcat_bf, Wr_bf, bcat);

    gemm_kernel<<<dim3(832), 256, 0, stream>>>(
        src_bf, Wcat_bf, pe_bf, Wr_bf, bcat, br, seq_len, QKb, VTg, Rpb);

    attn_kernel<<<dim3(8, NHn, Bn), 256, 0, stream>>>(QKb, VTg, Rpb, u, v, seq_len, Ob);

    ln_gelu_kernel<<<dim3(Bn * Ln / 4), 256, 0, stream>>>(src, Ob, gamma, beta, out);
}